// Round 4
// baseline (1580.138 us; speedup 1.0000x reference)
//
#include <hip/hip_runtime.h>
#include <stdint.h>

#define EMB 100
#define HW 50            // packed bf16 words per row
#define V4_PER_ROW 25
#define BSHIFT 8         // 256 rows per bucket
#define NBMAX 1024

// ---------------- bf16 helpers ----------------
static __device__ __forceinline__ uint32_t pack_bf16(float a, float b) {
    uint32_t ua = __float_as_uint(a);
    uint32_t ub = __float_as_uint(b);
    ua = (ua + 0x7FFFu + ((ua >> 16) & 1u)) >> 16;
    ub = (ub + 0x7FFFu + ((ub >> 16) & 1u)) >> 16;
    return ua | (ub << 16);
}
static __device__ __forceinline__ float bflo(uint32_t p) { return __uint_as_float(p << 16); }
static __device__ __forceinline__ float bfhi(uint32_t p) { return __uint_as_float(p & 0xFFFF0000u); }

__global__ void convert_bf16(const float2* __restrict__ x, uint32_t* __restrict__ xbf, int nwords) {
    for (int i = blockIdx.x * blockDim.x + threadIdx.x; i < nwords; i += gridDim.x * blockDim.x) {
        float2 v = x[i];
        xbf[i] = pack_bf16(v.x, v.y);
    }
}

// ---------------- batch-user map: map[user] = min slot ----------------
__global__ void map_build(const int* __restrict__ user, uint32_t* __restrict__ map, int batch) {
    int i = blockIdx.x * blockDim.x + threadIdx.x;
    if (i < batch) atomicMin(&map[user[i]], (uint32_t)i);
}

// ---------------- coarse bucket histogram (A full, U filtered), LDS-aggregated ----------------
__global__ void hist_buckets(const int* __restrict__ ra, int na,
                             const int* __restrict__ ru, int nu,
                             const uint32_t* __restrict__ map,
                             int* __restrict__ counts, int nbA, int nbTot) {
    __shared__ int lc[NBMAX];
    for (int i = threadIdx.x; i < nbTot; i += blockDim.x) lc[i] = 0;
    __syncthreads();
    const int n = na + nu;
    for (int e = blockIdx.x * blockDim.x + threadIdx.x; e < n; e += gridDim.x * blockDim.x) {
        if (e < na) {
            atomicAdd(&lc[__builtin_nontemporal_load(ra + e) >> BSHIFT], 1);
        } else {
            int r = __builtin_nontemporal_load(ru + (e - na));
            if (map[r] != 0xFFFFFFFFu) atomicAdd(&lc[nbA + (r >> BSHIFT)], 1);
        }
    }
    __syncthreads();
    for (int i = threadIdx.x; i < nbTot; i += blockDim.x)
        if (lc[i]) atomicAdd(&counts[i], lc[i]);
}

// ---------------- scan bucket counts -> bases & cursors (single block) ----------------
__global__ void scan_buckets(const int* __restrict__ counts, int* __restrict__ bases,
                             int* __restrict__ cursors, int nbTot,
                             int* __restrict__ rpA_end, int nnzA, int* __restrict__ rpU_end) {
    __shared__ int sh[1024];
    const int t = threadIdx.x;
    int v = (t < nbTot) ? counts[t] : 0;
    sh[t] = v;
    __syncthreads();
    for (int off = 1; off < 1024; off <<= 1) {
        int u = (t >= off) ? sh[t - off] : 0;
        __syncthreads();
        sh[t] += u;
        __syncthreads();
    }
    int incl = sh[t];
    int excl = incl - v;
    if (t < nbTot) { bases[t] = excl; cursors[t] = excl; }
    if (t == nbTot - 1) { bases[nbTot] = incl; *rpU_end = incl - nnzA; }
    if (t == 0) *rpA_end = nnzA;
}

// ---------------- bucket append: (rowlow|col, val) into bucket windows ----------------
__global__ void bucket_append(const float* __restrict__ va, const int* __restrict__ ra,
                              const int* __restrict__ ia, int na,
                              const float* __restrict__ vu, const int* __restrict__ ru,
                              const int* __restrict__ iu, int nu,
                              const uint32_t* __restrict__ map,
                              int* __restrict__ cursors, uint2* __restrict__ tmp, int nbA) {
    const int n = na + nu;
    for (int e = blockIdx.x * blockDim.x + threadIdx.x; e < n; e += gridDim.x * blockDim.x) {
        if (e < na) {
            int r = __builtin_nontemporal_load(ra + e);
            int p = atomicAdd(&cursors[r >> BSHIFT], 1);
            uint32_t key = ((uint32_t)(r & 255) << 17) | (uint32_t)__builtin_nontemporal_load(ia + e);
            tmp[p] = make_uint2(key, (uint32_t)__float_as_uint(__builtin_nontemporal_load(va + e)));
        } else {
            int k = e - na;
            int r = __builtin_nontemporal_load(ru + k);
            if (map[r] == 0xFFFFFFFFu) continue;
            int p = atomicAdd(&cursors[nbA + (r >> BSHIFT)], 1);
            uint32_t key = ((uint32_t)(r & 255) << 17) | (uint32_t)__builtin_nontemporal_load(iu + k);
            tmp[p] = make_uint2(key, (uint32_t)__float_as_uint(__builtin_nontemporal_load(vu + k)));
        }
    }
}

// ---------------- per-bucket fine sort -> packed 4B CSR + rowptr ----------------
__global__ __launch_bounds__(1024) void bucket_sort(const uint2* __restrict__ tmp,
                                                    const int* __restrict__ bases,
                                                    uint32_t* __restrict__ pk,
                                                    int* __restrict__ rpA, int* __restrict__ rpU,
                                                    int nbA, int nnzA, int nItems, int nUsers) {
    __shared__ int h[256];
    __shared__ int cur[256];
    const int t = threadIdx.x;
    const int b = blockIdx.x;
    const int lo = bases[b], hi = bases[b + 1];
    const bool isU = (b >= nbA);
    const int rowbase = (isU ? (b - nbA) : b) << BSHIFT;

    if (t < 256) h[t] = 0;
    __syncthreads();
    for (int i = lo + t; i < hi; i += 1024)
        atomicAdd(&h[tmp[i].x >> 17], 1);
    __syncthreads();
    int cnt = (t < 256) ? h[t] : 0;
    for (int off = 1; off < 256; off <<= 1) {
        int u = (t < 256 && t >= off) ? h[t - off] : 0;
        __syncthreads();
        if (t < 256) h[t] += u;
        __syncthreads();
    }
    if (t < 256) {
        int gpos = lo + h[t] - cnt;   // exclusive
        int row = rowbase + t;
        if (isU) { if (row < nUsers) rpU[row] = gpos - nnzA; }
        else     { if (row < nItems) rpA[row] = gpos; }
        cur[t] = gpos;
    }
    __syncthreads();
    for (int i = lo + t; i < hi; i += 1024) {
        uint2 e = tmp[i];
        int rl = (int)(e.x >> 17);
        uint32_t col = e.x & 0x1FFFFu;
        int p = atomicAdd(&cur[rl], 1);
        float v = __uint_as_float(e.y);
        uint32_t q = (uint32_t)(v * 32767.0f + 0.5f);
        if (q > 32767u) q = 32767u;
        pk[p] = (col << 15) | q;
    }
}

// ---------------- CSR SpMM, packed 4B elems, bf16 gathers, wave per row ----------------
#define DECODE(w, v, c) { v = (float)((w) & 0x7FFFu) * (1.0f/32767.0f); c = (int)((w) >> 15); }

__global__ __launch_bounds__(256) void spmm_pk(
    const uint32_t* __restrict__ pk, const int* __restrict__ rowptr,
    const uint32_t* __restrict__ xbf, uint32_t* __restrict__ outbf,
    const float2* __restrict__ emb2, const uint32_t* __restrict__ x1bf,
    const uint32_t* __restrict__ x2bf, float2* __restrict__ total2,
    uint32_t* __restrict__ totbf, int nrows)
{
    const int wid = (blockIdx.x * blockDim.x + threadIdx.x) >> 6;
    const int lane = threadIdx.x & 63;
    if (wid >= nrows) return;
    const int start = rowptr[wid], end = rowptr[wid + 1];
    float a0 = 0.f, a1 = 0.f;
    for (int base = start; base < end; base += 64) {
        const int nc = min(64, end - base);
        uint32_t w = 0;
        if (lane < nc) w = __builtin_nontemporal_load(pk + base + lane);
        float myv; int myc;
        DECODE(w, myv, myc);
        int t = 0;
        for (; t + 4 <= nc; t += 4) {
            float v0 = __shfl(myv, t),     v1 = __shfl(myv, t + 1);
            float v2 = __shfl(myv, t + 2), v3 = __shfl(myv, t + 3);
            int   c0 = __shfl(myc, t),     c1 = __shfl(myc, t + 1);
            int   c2 = __shfl(myc, t + 2), c3 = __shfl(myc, t + 3);
            uint32_t p0 = 0, p1 = 0, p2 = 0, p3 = 0;
            if (lane < HW) {
                p0 = xbf[(size_t)c0 * HW + lane];
                p1 = xbf[(size_t)c1 * HW + lane];
                p2 = xbf[(size_t)c2 * HW + lane];
                p3 = xbf[(size_t)c3 * HW + lane];
            }
            a0 = fmaf(v0, bflo(p0), a0); a1 = fmaf(v0, bfhi(p0), a1);
            a0 = fmaf(v1, bflo(p1), a0); a1 = fmaf(v1, bfhi(p1), a1);
            a0 = fmaf(v2, bflo(p2), a0); a1 = fmaf(v2, bfhi(p2), a1);
            a0 = fmaf(v3, bflo(p3), a0); a1 = fmaf(v3, bfhi(p3), a1);
        }
        for (; t < nc; ++t) {
            float v0 = __shfl(myv, t);
            int c0 = __shfl(myc, t);
            uint32_t p0 = 0;
            if (lane < HW) p0 = xbf[(size_t)c0 * HW + lane];
            a0 = fmaf(v0, bflo(p0), a0);
            a1 = fmaf(v0, bfhi(p0), a1);
        }
    }
    if (lane < HW) {
        const size_t widx = (size_t)wid * HW + lane;
        if (outbf) outbf[widx] = pack_bf16(a0, a1);
        if (total2) {
            float2 e = emb2[widx];
            uint32_t w1 = x1bf[widx], w2 = x2bf[widx];
            float t0 = e.x + bflo(w1) + bflo(w2) + a0;
            float t1 = e.y + bfhi(w1) + bfhi(w2) + a1;
            total2[widx] = make_float2(t0, t1);
            totbf[widx] = pack_bf16(t0, t1);
        }
    }
}

__global__ __launch_bounds__(256) void spmm_batch_pk(
    const uint32_t* __restrict__ pk, const int* __restrict__ rowptr,
    const int* __restrict__ user, const uint32_t* __restrict__ xbf,
    float2* __restrict__ out2, int batch)
{
    const int wid = (blockIdx.x * blockDim.x + threadIdx.x) >> 6;
    const int lane = threadIdx.x & 63;
    if (wid >= batch) return;
    const int row = user[wid];
    const int start = rowptr[row], end = rowptr[row + 1];
    float a0 = 0.f, a1 = 0.f;
    for (int base = start; base < end; base += 64) {
        const int nc = min(64, end - base);
        uint32_t w = 0;
        if (lane < nc) w = __builtin_nontemporal_load(pk + base + lane);
        float myv; int myc;
        DECODE(w, myv, myc);
        int t = 0;
        for (; t + 4 <= nc; t += 4) {
            float v0 = __shfl(myv, t),     v1 = __shfl(myv, t + 1);
            float v2 = __shfl(myv, t + 2), v3 = __shfl(myv, t + 3);
            int   c0 = __shfl(myc, t),     c1 = __shfl(myc, t + 1);
            int   c2 = __shfl(myc, t + 2), c3 = __shfl(myc, t + 3);
            uint32_t p0 = 0, p1 = 0, p2 = 0, p3 = 0;
            if (lane < HW) {
                p0 = xbf[(size_t)c0 * HW + lane];
                p1 = xbf[(size_t)c1 * HW + lane];
                p2 = xbf[(size_t)c2 * HW + lane];
                p3 = xbf[(size_t)c3 * HW + lane];
            }
            a0 = fmaf(v0, bflo(p0), a0); a1 = fmaf(v0, bfhi(p0), a1);
            a0 = fmaf(v1, bflo(p1), a0); a1 = fmaf(v1, bfhi(p1), a1);
            a0 = fmaf(v2, bflo(p2), a0); a1 = fmaf(v2, bfhi(p2), a1);
            a0 = fmaf(v3, bflo(p3), a0); a1 = fmaf(v3, bfhi(p3), a1);
        }
        for (; t < nc; ++t) {
            float v0 = __shfl(myv, t);
            int c0 = __shfl(myc, t);
            uint32_t p0 = 0;
            if (lane < HW) p0 = xbf[(size_t)c0 * HW + lane];
            a0 = fmaf(v0, bflo(p0), a0);
            a1 = fmaf(v0, bfhi(p0), a1);
        }
    }
    if (lane < HW) out2[(size_t)wid * HW + lane] = make_float2(a0, a1);
}

// ---------------- fallback (round-1) kernels ----------------
__global__ void spmm_scatter(const float* __restrict__ vals, const int* __restrict__ rows,
                             const int* __restrict__ cols, const float* __restrict__ x,
                             float* __restrict__ out, int nnz) {
    long long t = (long long)blockIdx.x * blockDim.x + threadIdx.x;
    int e = (int)(t / V4_PER_ROW);
    int c = (int)(t % V4_PER_ROW);
    if (e >= nnz) return;
    int col = cols[e]; int row = rows[e]; float v = vals[e];
    const float4 g = *(const float4*)(x + (size_t)col * EMB + c * 4);
    float* o = out + (size_t)row * EMB + c * 4;
    atomicAdd(o + 0, v * g.x); atomicAdd(o + 1, v * g.y);
    atomicAdd(o + 2, v * g.z); atomicAdd(o + 3, v * g.w);
}
__global__ void add_inplace(float* __restrict__ acc, const float* __restrict__ x, int n4) {
    int i = blockIdx.x * blockDim.x + threadIdx.x;
    if (i < n4) {
        float4 a = ((const float4*)acc)[i];
        const float4 b = ((const float4*)x)[i];
        a.x += b.x; a.y += b.y; a.z += b.z; a.w += b.w;
        ((float4*)acc)[i] = a;
    }
}
__global__ void gather_rows(const float* __restrict__ src, const int* __restrict__ idx,
                            float* __restrict__ out, int nrows) {
    int t = blockIdx.x * blockDim.x + threadIdx.x;
    int r = t / V4_PER_ROW, c = t % V4_PER_ROW;
    if (r >= nrows) return;
    int s = idx[r];
    *(float4*)(out + (size_t)r * EMB + c * 4) = *(const float4*)(src + (size_t)s * EMB + c * 4);
}

// ---------------- launch ----------------
static inline size_t align256(size_t x) { return (x + 255) & ~(size_t)255; }

extern "C" void kernel_launch(void* const* d_in, const int* in_sizes, int n_in,
                              void* d_out, int out_size, void* d_ws, size_t ws_size,
                              hipStream_t stream) {
    const float* adj_vals  = (const float*)d_in[0];
    const float* u_vals    = (const float*)d_in[1];
    const float* embedding = (const float*)d_in[2];
    const int*   adj_rows  = (const int*)d_in[4];
    const int*   adj_cols  = (const int*)d_in[5];
    const int*   u_rows    = (const int*)d_in[6];
    const int*   u_cols    = (const int*)d_in[7];
    const int*   user      = (const int*)d_in[8];

    const int NNZ_A   = in_sizes[0];
    const int NNZ_U   = in_sizes[1];
    const int N_ITEMS = in_sizes[2] / EMB;
    const int N_USERS = in_sizes[3] / EMB;
    const int BATCH   = in_sizes[8];

    const int NB_A = (N_ITEMS + 255) >> BSHIFT;
    const int NB_U = (N_USERS + 255) >> BSHIFT;
    const int NB_TOT = NB_A + NB_U;

    float* total    = (float*)d_out;
    float* out_user = total + (size_t)N_ITEMS * EMB;

    const size_t rowWords = (size_t)N_ITEMS * HW;   // bf16-packed words per item matrix

    // ---- workspace layout ----
    size_t off = 0;
    char* ws = (char*)d_ws;
    #define WS_ALLOC(name, bytes) char* name = ws + off; off += align256(bytes)
    WS_ALLOC(p_r0,     2 * rowWords * 4);                    // x1bf|x2bf, aliased by tmp
    WS_ALLOC(p_ebf,    rowWords * 4);                        // embbf -> totbf
    WS_ALLOC(p_pk,     ((size_t)NNZ_A + NNZ_U) * 4);         // packed CSR (A then U)
    WS_ALLOC(p_rpA,    ((size_t)N_ITEMS + 1) * 4);
    WS_ALLOC(p_rpU,    ((size_t)N_USERS + 1) * 4);
    WS_ALLOC(p_map,    (size_t)N_USERS * 4);
    WS_ALLOC(p_counts, (size_t)NB_TOT * 4);
    WS_ALLOC(p_bases,  ((size_t)NB_TOT + 1) * 4);
    WS_ALLOC(p_curs,   (size_t)NB_TOT * 4);
    #undef WS_ALLOC
    const size_t tmpBytes = ((size_t)NNZ_A + NNZ_U) * 8;     // uint2 per nnz, aliases p_r0

    if (ws_size >= off && tmpBytes <= 2 * rowWords * 4 && NB_TOT <= NBMAX) {
        uint32_t* x1bf  = (uint32_t*)p_r0;
        uint32_t* x2bf  = (uint32_t*)(p_r0 + rowWords * 4);
        uint2*    tmp   = (uint2*)p_r0;                      // dead before x1bf is written
        uint32_t* embbf = (uint32_t*)p_ebf;
        uint32_t* totbf = (uint32_t*)p_ebf;                  // embbf dead after layer 1
        uint32_t* pk    = (uint32_t*)p_pk;
        int* rpA = (int*)p_rpA;
        int* rpU = (int*)p_rpU;
        uint32_t* map = (uint32_t*)p_map;
        int* counts = (int*)p_counts;
        int* bases  = (int*)p_bases;
        int* curs   = (int*)p_curs;

        // batch-user map
        hipMemsetAsync(map, 0xFF, (size_t)N_USERS * 4, stream);
        map_build<<<(BATCH + 255) / 256, 256, 0, stream>>>(user, map, BATCH);

        // embedding -> packed bf16
        convert_bf16<<<2048, 256, 0, stream>>>((const float2*)embedding, embbf, (int)rowWords);

        // bucket histogram -> scan -> append -> fine sort
        hipMemsetAsync(counts, 0, (size_t)NB_TOT * 4, stream);
        hist_buckets<<<1024, 256, 0, stream>>>(adj_rows, NNZ_A, u_rows, NNZ_U, map,
                                               counts, NB_A, NB_TOT);
        scan_buckets<<<1, 1024, 0, stream>>>(counts, bases, curs, NB_TOT,
                                             rpA + N_ITEMS, NNZ_A, rpU + N_USERS);
        bucket_append<<<2048, 256, 0, stream>>>(adj_vals, adj_rows, adj_cols, NNZ_A,
                                                u_vals, u_rows, u_cols, NNZ_U,
                                                map, curs, tmp, NB_A);
        bucket_sort<<<NB_TOT, 1024, 0, stream>>>(tmp, bases, pk, rpA, rpU,
                                                 NB_A, NNZ_A, N_ITEMS, N_USERS);

        const int gridA = (N_ITEMS + 3) / 4;   // 4 waves per 256-thread block
        // L1: x1 = A emb
        spmm_pk<<<gridA, 256, 0, stream>>>(pk, rpA, embbf, x1bf,
                                           nullptr, nullptr, nullptr, nullptr, nullptr, N_ITEMS);
        // L2: x2 = A x1
        spmm_pk<<<gridA, 256, 0, stream>>>(pk, rpA, x1bf, x2bf,
                                           nullptr, nullptr, nullptr, nullptr, nullptr, N_ITEMS);
        // L3: acc = A x2 ; total = emb + x1 + x2 + acc ; totbf = pack(total)
        spmm_pk<<<gridA, 256, 0, stream>>>(pk, rpA, x2bf, nullptr,
                                           (const float2*)embedding, x1bf, x2bf,
                                           (float2*)total, totbf, N_ITEMS);
        // batch user rows: out_user = (U @ total)[user]  (U CSR covers batch users only)
        const int gridB = (BATCH + 3) / 4;
        spmm_batch_pk<<<gridB, 256, 0, stream>>>(pk + NNZ_A, rpU, user, totbf,
                                                 (float2*)out_user, BATCH);
    } else {
        // ---- fallback: round-1 atomic path ----
        const size_t itemBytes = (size_t)N_ITEMS * EMB * sizeof(float);
        float* buf0 = (float*)d_ws;
        float* buf1 = buf0 + (size_t)N_ITEMS * EMB;
        float* user_all = buf1;
        const size_t userBytes = (size_t)N_USERS * EMB * sizeof(float);

        hipMemcpyAsync(total, embedding, itemBytes, hipMemcpyDeviceToDevice, stream);
        const int blkA = (NNZ_A * V4_PER_ROW + 255) / 256;
        const int blkU = (NNZ_U * V4_PER_ROW + 255) / 256;
        const int n4 = N_ITEMS * EMB / 4;
        const int blkAdd = (n4 + 255) / 256;

        hipMemsetAsync(buf0, 0, itemBytes, stream);
        spmm_scatter<<<blkA, 256, 0, stream>>>(adj_vals, adj_rows, adj_cols, embedding, buf0, NNZ_A);
        add_inplace<<<blkAdd, 256, 0, stream>>>(total, buf0, n4);
        hipMemsetAsync(buf1, 0, itemBytes, stream);
        spmm_scatter<<<blkA, 256, 0, stream>>>(adj_vals, adj_rows, adj_cols, buf0, buf1, NNZ_A);
        add_inplace<<<blkAdd, 256, 0, stream>>>(total, buf1, n4);
        hipMemsetAsync(buf0, 0, itemBytes, stream);
        spmm_scatter<<<blkA, 256, 0, stream>>>(adj_vals, adj_rows, adj_cols, buf1, buf0, NNZ_A);
        add_inplace<<<blkAdd, 256, 0, stream>>>(total, buf0, n4);
        hipMemsetAsync(user_all, 0, userBytes, stream);
        spmm_scatter<<<blkU, 256, 0, stream>>>(u_vals, u_rows, u_cols, total, user_all, NNZ_U);
        gather_rows<<<(BATCH * V4_PER_ROW + 255) / 256, 256, 0, stream>>>(user_all, user, out_user, BATCH);
    }
}

// Round 5
// 553.215 us; speedup vs baseline: 2.8563x; 2.8563x over previous
//
#include <hip/hip_runtime.h>
#include <stdint.h>

#define EMB 100
#define HW 50            // packed bf16 words per row
#define V4_PER_ROW 25
#define BSHIFT 8         // 256 rows per bucket
#define NBMAX 1024
#define TP 256           // threads per pass block
#define EP 16            // elements per thread in pass kernels (4096/block)

// ---------------- bf16 helpers ----------------
static __device__ __forceinline__ uint32_t pack_bf16(float a, float b) {
    uint32_t ua = __float_as_uint(a);
    uint32_t ub = __float_as_uint(b);
    ua = (ua + 0x7FFFu + ((ua >> 16) & 1u)) >> 16;
    ub = (ub + 0x7FFFu + ((ub >> 16) & 1u)) >> 16;
    return ua | (ub << 16);
}
static __device__ __forceinline__ float bflo(uint32_t p) { return __uint_as_float(p << 16); }
static __device__ __forceinline__ float bfhi(uint32_t p) { return __uint_as_float(p & 0xFFFF0000u); }

__global__ void convert_bf16(const float2* __restrict__ x, uint32_t* __restrict__ xbf, int nwords) {
    for (int i = blockIdx.x * blockDim.x + threadIdx.x; i < nwords; i += gridDim.x * blockDim.x) {
        float2 v = x[i];
        xbf[i] = pack_bf16(v.x, v.y);
    }
}

// ---------------- batch-user map ----------------
__global__ void map_build(const int* __restrict__ user, uint32_t* __restrict__ map, int batch) {
    int i = blockIdx.x * blockDim.x + threadIdx.x;
    if (i < batch) atomicMin(&map[user[i]], (uint32_t)i);
}

// ---------------- pass 1: per-(block,bucket) counts, no global atomics ----------------
__global__ __launch_bounds__(TP) void pass1_count(
    const int* __restrict__ ra, int na, const int* __restrict__ ru, int nu,
    const uint32_t* __restrict__ map, int* __restrict__ countsT,
    int nblk, int nbA, int nbTot)
{
    __shared__ int lc[NBMAX];
    const int blk = blockIdx.x;
    for (int i = threadIdx.x; i < nbTot; i += TP) lc[i] = 0;
    __syncthreads();
    const int base = blk * (TP * EP);
    const int n = na + nu;
    for (int i = 0; i < EP; ++i) {
        int e = base + i * TP + threadIdx.x;
        int b = -1;
        if (e < na) {
            b = __builtin_nontemporal_load(ra + e) >> BSHIFT;
        } else if (e < n) {
            int r = __builtin_nontemporal_load(ru + (e - na));
            if (map[r] != 0xFFFFFFFFu) b = nbA + (r >> BSHIFT);
        }
        if (b >= 0) atomicAdd(&lc[b], 1);
    }
    __syncthreads();
    for (int i = threadIdx.x; i < nbTot; i += TP)
        countsT[(size_t)i * nblk + blk] = lc[i];
}

// ---------------- 3-phase exclusive scan over countsT ----------------
#define SCAN_T 256
#define SCAN_E 16

__global__ void scan_blocks(const int* __restrict__ in, int* __restrict__ out,
                            int* __restrict__ sums, int n) {
    __shared__ int smem[SCAN_T];
    const int b = blockIdx.x, tid = threadIdx.x;
    const int base = b * SCAN_T * SCAN_E + tid * SCAN_E;
    int loc[SCAN_E];
    int s = 0;
    for (int i = 0; i < SCAN_E; ++i) {
        int idx = base + i;
        int v = (idx < n) ? in[idx] : 0;
        loc[i] = s; s += v;
    }
    smem[tid] = s; __syncthreads();
    for (int off = 1; off < SCAN_T; off <<= 1) {
        int v = (tid >= off) ? smem[tid - off] : 0;
        __syncthreads();
        smem[tid] += v;
        __syncthreads();
    }
    int pre = (tid == 0) ? 0 : smem[tid - 1];
    if (tid == SCAN_T - 1) sums[b] = smem[tid];
    for (int i = 0; i < SCAN_E; ++i) {
        int idx = base + i;
        if (idx < n) out[idx] = pre + loc[i];
    }
}

// inclusive scan of <=256 block sums; writes grand total
__global__ void scan_mid(int* __restrict__ sums, int nb, int* __restrict__ total_out) {
    __shared__ int sh[256];
    const int t = threadIdx.x;
    int v = (t < nb) ? sums[t] : 0;
    sh[t] = v; __syncthreads();
    for (int off = 1; off < 256; off <<= 1) {
        int u = (t >= off) ? sh[t - off] : 0;
        __syncthreads();
        sh[t] += u;
        __syncthreads();
    }
    if (t < nb) sums[t] = sh[t];
    if (t == 255) *total_out = sh[255];
}

__global__ void scan_fixup(int* __restrict__ out, const int* __restrict__ sums, int n) {
    const int b = blockIdx.x;
    if (b == 0) return;
    const int add = sums[b - 1];
    const int base = b * SCAN_T * SCAN_E + threadIdx.x * SCAN_E;
    for (int i = 0; i < SCAN_E; ++i) {
        int idx = base + i;
        if (idx < n) out[idx] += add;
    }
}

// bases[b] = scanned[b*nblk]; plus rowptr ends
__global__ void extract_bases(const int* __restrict__ scanned, int nblk, int nbTot,
                              const int* __restrict__ total, int* __restrict__ bases,
                              int* __restrict__ rpA_end, int nnzA, int* __restrict__ rpU_end) {
    int t = blockIdx.x * blockDim.x + threadIdx.x;
    if (t < nbTot) bases[t] = scanned[(size_t)t * nblk];
    if (t == 0) {
        int tot = *total;
        bases[nbTot] = tot;
        *rpA_end = nnzA;
        *rpU_end = tot - nnzA;
    }
}

// ---------------- pass 2: scatter into bucket-partitioned tmp, no global atomics ----------------
__global__ __launch_bounds__(TP) void pass2_scatter(
    const float* __restrict__ va, const int* __restrict__ ra, const int* __restrict__ ia, int na,
    const float* __restrict__ vu, const int* __restrict__ ru, const int* __restrict__ iu, int nu,
    const uint32_t* __restrict__ map, const int* __restrict__ scanned,
    uint2* __restrict__ tmp, int nblk, int nbA, int nbTot)
{
    __shared__ int cur[NBMAX];
    const int blk = blockIdx.x;
    for (int i = threadIdx.x; i < nbTot; i += TP)
        cur[i] = scanned[(size_t)i * nblk + blk];
    __syncthreads();
    const int base = blk * (TP * EP);
    const int n = na + nu;
    for (int i = 0; i < EP; ++i) {
        int e = base + i * TP + threadIdx.x;
        if (e < na) {
            int r = __builtin_nontemporal_load(ra + e);
            int p = atomicAdd(&cur[r >> BSHIFT], 1);
            uint32_t key = ((uint32_t)(r & 255) << 17) | (uint32_t)__builtin_nontemporal_load(ia + e);
            tmp[p] = make_uint2(key, (uint32_t)__float_as_uint(__builtin_nontemporal_load(va + e)));
        } else if (e < n) {
            int k = e - na;
            int r = __builtin_nontemporal_load(ru + k);
            if (map[r] == 0xFFFFFFFFu) continue;
            int p = atomicAdd(&cur[nbA + (r >> BSHIFT)], 1);
            uint32_t key = ((uint32_t)(r & 255) << 17) | (uint32_t)__builtin_nontemporal_load(iu + k);
            tmp[p] = make_uint2(key, (uint32_t)__float_as_uint(__builtin_nontemporal_load(vu + k)));
        }
    }
}

// ---------------- per-bucket fine sort -> packed 4B CSR + rowptr ----------------
__global__ __launch_bounds__(1024) void bucket_sort(const uint2* __restrict__ tmp,
                                                    const int* __restrict__ bases,
                                                    uint32_t* __restrict__ pk,
                                                    int* __restrict__ rpA, int* __restrict__ rpU,
                                                    int nbA, int nnzA, int nItems, int nUsers) {
    __shared__ int h[256];
    __shared__ int cur[256];
    const int t = threadIdx.x;
    const int b = blockIdx.x;
    const int lo = bases[b], hi = bases[b + 1];
    const bool isU = (b >= nbA);
    const int rowbase = (isU ? (b - nbA) : b) << BSHIFT;

    if (t < 256) h[t] = 0;
    __syncthreads();
    for (int i = lo + t; i < hi; i += 1024)
        atomicAdd(&h[tmp[i].x >> 17], 1);
    __syncthreads();
    int cnt = (t < 256) ? h[t] : 0;
    for (int off = 1; off < 256; off <<= 1) {
        int u = (t < 256 && t >= off) ? h[t - off] : 0;
        __syncthreads();
        if (t < 256) h[t] += u;
        __syncthreads();
    }
    if (t < 256) {
        int gpos = lo + h[t] - cnt;   // exclusive
        int row = rowbase + t;
        if (isU) { if (row < nUsers) rpU[row] = gpos - nnzA; }
        else     { if (row < nItems) rpA[row] = gpos; }
        cur[t] = gpos;
    }
    __syncthreads();
    for (int i = lo + t; i < hi; i += 1024) {
        uint2 e = tmp[i];
        int rl = (int)(e.x >> 17);
        uint32_t col = e.x & 0x1FFFFu;
        int p = atomicAdd(&cur[rl], 1);
        float v = __uint_as_float(e.y);
        uint32_t q = (uint32_t)(v * 32767.0f + 0.5f);
        if (q > 32767u) q = 32767u;
        pk[p] = (col << 15) | q;
    }
}

// ---------------- CSR SpMM, packed 4B elems, bf16 gathers, wave per row ----------------
#define DECODE(w, v, c) { v = (float)((w) & 0x7FFFu) * (1.0f/32767.0f); c = (int)((w) >> 15); }

__global__ __launch_bounds__(256) void spmm_pk(
    const uint32_t* __restrict__ pk, const int* __restrict__ rowptr,
    const uint32_t* __restrict__ xbf, uint32_t* __restrict__ outbf,
    const float2* __restrict__ emb2, const uint32_t* __restrict__ x1bf,
    const uint32_t* __restrict__ x2bf, float2* __restrict__ total2,
    uint32_t* __restrict__ totbf, int nrows)
{
    const int wid = (blockIdx.x * blockDim.x + threadIdx.x) >> 6;
    const int lane = threadIdx.x & 63;
    if (wid >= nrows) return;
    const int start = rowptr[wid], end = rowptr[wid + 1];
    float a0 = 0.f, a1 = 0.f;
    for (int base = start; base < end; base += 64) {
        const int nc = min(64, end - base);
        uint32_t w = 0;
        if (lane < nc) w = __builtin_nontemporal_load(pk + base + lane);
        float myv; int myc;
        DECODE(w, myv, myc);
        int t = 0;
        for (; t + 4 <= nc; t += 4) {
            float v0 = __shfl(myv, t),     v1 = __shfl(myv, t + 1);
            float v2 = __shfl(myv, t + 2), v3 = __shfl(myv, t + 3);
            int   c0 = __shfl(myc, t),     c1 = __shfl(myc, t + 1);
            int   c2 = __shfl(myc, t + 2), c3 = __shfl(myc, t + 3);
            uint32_t p0 = 0, p1 = 0, p2 = 0, p3 = 0;
            if (lane < HW) {
                p0 = xbf[(size_t)c0 * HW + lane];
                p1 = xbf[(size_t)c1 * HW + lane];
                p2 = xbf[(size_t)c2 * HW + lane];
                p3 = xbf[(size_t)c3 * HW + lane];
            }
            a0 = fmaf(v0, bflo(p0), a0); a1 = fmaf(v0, bfhi(p0), a1);
            a0 = fmaf(v1, bflo(p1), a0); a1 = fmaf(v1, bfhi(p1), a1);
            a0 = fmaf(v2, bflo(p2), a0); a1 = fmaf(v2, bfhi(p2), a1);
            a0 = fmaf(v3, bflo(p3), a0); a1 = fmaf(v3, bfhi(p3), a1);
        }
        for (; t < nc; ++t) {
            float v0 = __shfl(myv, t);
            int c0 = __shfl(myc, t);
            uint32_t p0 = 0;
            if (lane < HW) p0 = xbf[(size_t)c0 * HW + lane];
            a0 = fmaf(v0, bflo(p0), a0);
            a1 = fmaf(v0, bfhi(p0), a1);
        }
    }
    if (lane < HW) {
        const size_t widx = (size_t)wid * HW + lane;
        if (outbf) outbf[widx] = pack_bf16(a0, a1);
        if (total2) {
            float2 e = emb2[widx];
            uint32_t w1 = x1bf[widx], w2 = x2bf[widx];
            float t0 = e.x + bflo(w1) + bflo(w2) + a0;
            float t1 = e.y + bfhi(w1) + bfhi(w2) + a1;
            total2[widx] = make_float2(t0, t1);
            totbf[widx] = pack_bf16(t0, t1);
        }
    }
}

__global__ __launch_bounds__(256) void spmm_batch_pk(
    const uint32_t* __restrict__ pk, const int* __restrict__ rowptr,
    const int* __restrict__ user, const uint32_t* __restrict__ xbf,
    float2* __restrict__ out2, int batch)
{
    const int wid = (blockIdx.x * blockDim.x + threadIdx.x) >> 6;
    const int lane = threadIdx.x & 63;
    if (wid >= batch) return;
    const int row = user[wid];
    const int start = rowptr[row], end = rowptr[row + 1];
    float a0 = 0.f, a1 = 0.f;
    for (int base = start; base < end; base += 64) {
        const int nc = min(64, end - base);
        uint32_t w = 0;
        if (lane < nc) w = __builtin_nontemporal_load(pk + base + lane);
        float myv; int myc;
        DECODE(w, myv, myc);
        int t = 0;
        for (; t + 4 <= nc; t += 4) {
            float v0 = __shfl(myv, t),     v1 = __shfl(myv, t + 1);
            float v2 = __shfl(myv, t + 2), v3 = __shfl(myv, t + 3);
            int   c0 = __shfl(myc, t),     c1 = __shfl(myc, t + 1);
            int   c2 = __shfl(myc, t + 2), c3 = __shfl(myc, t + 3);
            uint32_t p0 = 0, p1 = 0, p2 = 0, p3 = 0;
            if (lane < HW) {
                p0 = xbf[(size_t)c0 * HW + lane];
                p1 = xbf[(size_t)c1 * HW + lane];
                p2 = xbf[(size_t)c2 * HW + lane];
                p3 = xbf[(size_t)c3 * HW + lane];
            }
            a0 = fmaf(v0, bflo(p0), a0); a1 = fmaf(v0, bfhi(p0), a1);
            a0 = fmaf(v1, bflo(p1), a0); a1 = fmaf(v1, bfhi(p1), a1);
            a0 = fmaf(v2, bflo(p2), a0); a1 = fmaf(v2, bfhi(p2), a1);
            a0 = fmaf(v3, bflo(p3), a0); a1 = fmaf(v3, bfhi(p3), a1);
        }
        for (; t < nc; ++t) {
            float v0 = __shfl(myv, t);
            int c0 = __shfl(myc, t);
            uint32_t p0 = 0;
            if (lane < HW) p0 = xbf[(size_t)c0 * HW + lane];
            a0 = fmaf(v0, bflo(p0), a0);
            a1 = fmaf(v0, bfhi(p0), a1);
        }
    }
    if (lane < HW) out2[(size_t)wid * HW + lane] = make_float2(a0, a1);
}

// ---------------- fallback (round-1) kernels ----------------
__global__ void spmm_scatter(const float* __restrict__ vals, const int* __restrict__ rows,
                             const int* __restrict__ cols, const float* __restrict__ x,
                             float* __restrict__ out, int nnz) {
    long long t = (long long)blockIdx.x * blockDim.x + threadIdx.x;
    int e = (int)(t / V4_PER_ROW);
    int c = (int)(t % V4_PER_ROW);
    if (e >= nnz) return;
    int col = cols[e]; int row = rows[e]; float v = vals[e];
    const float4 g = *(const float4*)(x + (size_t)col * EMB + c * 4);
    float* o = out + (size_t)row * EMB + c * 4;
    atomicAdd(o + 0, v * g.x); atomicAdd(o + 1, v * g.y);
    atomicAdd(o + 2, v * g.z); atomicAdd(o + 3, v * g.w);
}
__global__ void add_inplace(float* __restrict__ acc, const float* __restrict__ x, int n4) {
    int i = blockIdx.x * blockDim.x + threadIdx.x;
    if (i < n4) {
        float4 a = ((const float4*)acc)[i];
        const float4 b = ((const float4*)x)[i];
        a.x += b.x; a.y += b.y; a.z += b.z; a.w += b.w;
        ((float4*)acc)[i] = a;
    }
}
__global__ void gather_rows(const float* __restrict__ src, const int* __restrict__ idx,
                            float* __restrict__ out, int nrows) {
    int t = blockIdx.x * blockDim.x + threadIdx.x;
    int r = t / V4_PER_ROW, c = t % V4_PER_ROW;
    if (r >= nrows) return;
    int s = idx[r];
    *(float4*)(out + (size_t)r * EMB + c * 4) = *(const float4*)(src + (size_t)s * EMB + c * 4);
}

// ---------------- launch ----------------
static inline size_t align256(size_t x) { return (x + 255) & ~(size_t)255; }

extern "C" void kernel_launch(void* const* d_in, const int* in_sizes, int n_in,
                              void* d_out, int out_size, void* d_ws, size_t ws_size,
                              hipStream_t stream) {
    const float* adj_vals  = (const float*)d_in[0];
    const float* u_vals    = (const float*)d_in[1];
    const float* embedding = (const float*)d_in[2];
    const int*   adj_rows  = (const int*)d_in[4];
    const int*   adj_cols  = (const int*)d_in[5];
    const int*   u_rows    = (const int*)d_in[6];
    const int*   u_cols    = (const int*)d_in[7];
    const int*   user      = (const int*)d_in[8];

    const int NNZ_A   = in_sizes[0];
    const int NNZ_U   = in_sizes[1];
    const int N_ITEMS = in_sizes[2] / EMB;
    const int N_USERS = in_sizes[3] / EMB;
    const int BATCH   = in_sizes[8];

    const int NB_A = (N_ITEMS + 255) >> BSHIFT;
    const int NB_U = (N_USERS + 255) >> BSHIFT;
    const int NB_TOT = NB_A + NB_U;

    const int NNZ_T = NNZ_A + NNZ_U;
    const int nblk = (NNZ_T + TP * EP - 1) / (TP * EP);           // pass-kernel blocks
    const long long nScan = (long long)NB_TOT * nblk;             // counts matrix size
    const int nsb = (int)((nScan + SCAN_T * SCAN_E - 1) / (SCAN_T * SCAN_E));

    float* total    = (float*)d_out;
    float* out_user = total + (size_t)N_ITEMS * EMB;

    const size_t rowWords = (size_t)N_ITEMS * HW;

    // ---- workspace layout ----
    size_t off = 0;
    char* ws = (char*)d_ws;
    #define WS_ALLOC(name, bytes) char* name = ws + off; off += align256(bytes)
    WS_ALLOC(p_r0,      2 * rowWords * 4);               // x1bf|x2bf, aliased by tmp
    WS_ALLOC(p_ebf,     rowWords * 4);                   // embbf -> totbf
    WS_ALLOC(p_pk,      (size_t)NNZ_T * 4);              // packed CSR (A then U)
    WS_ALLOC(p_rpA,     ((size_t)N_ITEMS + 1) * 4);
    WS_ALLOC(p_rpU,     ((size_t)N_USERS + 1) * 4);
    WS_ALLOC(p_map,     (size_t)N_USERS * 4);
    WS_ALLOC(p_countsT, (size_t)nScan * 4);              // per-(bucket,block) counts -> scanned
    WS_ALLOC(p_sums,    256 * 4);
    WS_ALLOC(p_total,   4);
    WS_ALLOC(p_bases,   ((size_t)NB_TOT + 1) * 4);
    #undef WS_ALLOC
    const size_t tmpBytes = (size_t)NNZ_T * 8;           // uint2 per nnz, aliases p_r0

    if (ws_size >= off && tmpBytes <= 2 * rowWords * 4 && NB_TOT <= NBMAX && nsb <= 256) {
        uint32_t* x1bf  = (uint32_t*)p_r0;
        uint32_t* x2bf  = (uint32_t*)(p_r0 + rowWords * 4);
        uint2*    tmp   = (uint2*)p_r0;                  // dead before x1bf is written
        uint32_t* embbf = (uint32_t*)p_ebf;
        uint32_t* totbf = (uint32_t*)p_ebf;              // embbf dead after layer 1
        uint32_t* pk    = (uint32_t*)p_pk;
        int* rpA = (int*)p_rpA;
        int* rpU = (int*)p_rpU;
        uint32_t* map = (uint32_t*)p_map;
        int* countsT = (int*)p_countsT;
        int* sums    = (int*)p_sums;
        int* totalN  = (int*)p_total;
        int* bases   = (int*)p_bases;

        // batch-user map
        hipMemsetAsync(map, 0xFF, (size_t)N_USERS * 4, stream);
        map_build<<<(BATCH + 255) / 256, 256, 0, stream>>>(user, map, BATCH);

        // embedding -> packed bf16
        convert_bf16<<<2048, 256, 0, stream>>>((const float2*)embedding, embbf, (int)rowWords);

        // --- deterministic two-pass bucket partition (no global atomics) ---
        pass1_count<<<nblk, TP, 0, stream>>>(adj_rows, NNZ_A, u_rows, NNZ_U, map,
                                             countsT, nblk, NB_A, NB_TOT);
        scan_blocks<<<nsb, SCAN_T, 0, stream>>>(countsT, countsT, sums, (int)nScan);
        scan_mid<<<1, 256, 0, stream>>>(sums, nsb, totalN);
        scan_fixup<<<nsb, SCAN_T, 0, stream>>>(countsT, sums, (int)nScan);
        extract_bases<<<(NB_TOT + 255) / 256, 256, 0, stream>>>(countsT, nblk, NB_TOT, totalN,
                                                                bases, rpA + N_ITEMS, NNZ_A,
                                                                rpU + N_USERS);
        pass2_scatter<<<nblk, TP, 0, stream>>>(adj_vals, adj_rows, adj_cols, NNZ_A,
                                               u_vals, u_rows, u_cols, NNZ_U,
                                               map, countsT, tmp, nblk, NB_A, NB_TOT);
        bucket_sort<<<NB_TOT, 1024, 0, stream>>>(tmp, bases, pk, rpA, rpU,
                                                 NB_A, NNZ_A, N_ITEMS, N_USERS);

        const int gridA = (N_ITEMS + 3) / 4;   // 4 waves per 256-thread block
        // L1: x1 = A emb
        spmm_pk<<<gridA, 256, 0, stream>>>(pk, rpA, embbf, x1bf,
                                           nullptr, nullptr, nullptr, nullptr, nullptr, N_ITEMS);
        // L2: x2 = A x1
        spmm_pk<<<gridA, 256, 0, stream>>>(pk, rpA, x1bf, x2bf,
                                           nullptr, nullptr, nullptr, nullptr, nullptr, N_ITEMS);
        // L3: acc = A x2 ; total = emb + x1 + x2 + acc ; totbf = pack(total)
        spmm_pk<<<gridA, 256, 0, stream>>>(pk, rpA, x2bf, nullptr,
                                           (const float2*)embedding, x1bf, x2bf,
                                           (float2*)total, totbf, N_ITEMS);
        // batch user rows: out_user = (U @ total)[user]
        const int gridB = (BATCH + 3) / 4;
        spmm_batch_pk<<<gridB, 256, 0, stream>>>(pk + NNZ_A, rpU, user, totbf,
                                                 (float2*)out_user, BATCH);
    } else {
        // ---- fallback: round-1 atomic path ----
        const size_t itemBytes = (size_t)N_ITEMS * EMB * sizeof(float);
        float* buf0 = (float*)d_ws;
        float* buf1 = buf0 + (size_t)N_ITEMS * EMB;
        float* user_all = buf1;
        const size_t userBytes = (size_t)N_USERS * EMB * sizeof(float);

        hipMemcpyAsync(total, embedding, itemBytes, hipMemcpyDeviceToDevice, stream);
        const int blkA = (NNZ_A * V4_PER_ROW + 255) / 256;
        const int blkU = (NNZ_U * V4_PER_ROW + 255) / 256;
        const int n4 = N_ITEMS * EMB / 4;
        const int blkAdd = (n4 + 255) / 256;

        hipMemsetAsync(buf0, 0, itemBytes, stream);
        spmm_scatter<<<blkA, 256, 0, stream>>>(adj_vals, adj_rows, adj_cols, embedding, buf0, NNZ_A);
        add_inplace<<<blkAdd, 256, 0, stream>>>(total, buf0, n4);
        hipMemsetAsync(buf1, 0, itemBytes, stream);
        spmm_scatter<<<blkA, 256, 0, stream>>>(adj_vals, adj_rows, adj_cols, buf0, buf1, NNZ_A);
        add_inplace<<<blkAdd, 256, 0, stream>>>(total, buf1, n4);
        hipMemsetAsync(buf0, 0, itemBytes, stream);
        spmm_scatter<<<blkA, 256, 0, stream>>>(adj_vals, adj_rows, adj_cols, buf1, buf0, NNZ_A);
        add_inplace<<<blkAdd, 256, 0, stream>>>(total, buf0, n4);
        hipMemsetAsync(user_all, 0, userBytes, stream);
        spmm_scatter<<<blkU, 256, 0, stream>>>(u_vals, u_rows, u_cols, total, user_all, NNZ_U);
        gather_rows<<<(BATCH * V4_PER_ROW + 255) / 256, 256, 0, stream>>>(user_all, user, out_user, BATCH);
    }
}

// Round 6
// 549.262 us; speedup vs baseline: 2.8768x; 1.0072x over previous
//
#include <hip/hip_runtime.h>
#include <stdint.h>

#define EMB 100
#define HW 50            // packed bf16 words per row
#define V4_PER_ROW 25
#define BSHIFT 8         // 256 rows per bucket
#define NBMAX 1024
#define TP 256           // threads per pass block
#define EP 16            // elements per thread in pass kernels (4096/block)
#define BANDSH 13        // column band = col >> 13  (16 bands over 2^17 cols)
#define NBIN 4096        // 256 rowlow x 16 bands

// ---------------- bf16 helpers ----------------
static __device__ __forceinline__ uint32_t pack_bf16(float a, float b) {
    uint32_t ua = __float_as_uint(a);
    uint32_t ub = __float_as_uint(b);
    ua = (ua + 0x7FFFu + ((ua >> 16) & 1u)) >> 16;
    ub = (ub + 0x7FFFu + ((ub >> 16) & 1u)) >> 16;
    return ua | (ub << 16);
}
static __device__ __forceinline__ float bflo(uint32_t p) { return __uint_as_float(p << 16); }
static __device__ __forceinline__ float bfhi(uint32_t p) { return __uint_as_float(p & 0xFFFF0000u); }

__global__ void convert_bf16(const float2* __restrict__ x, uint32_t* __restrict__ xbf, int nwords) {
    for (int i = blockIdx.x * blockDim.x + threadIdx.x; i < nwords; i += gridDim.x * blockDim.x) {
        float2 v = x[i];
        xbf[i] = pack_bf16(v.x, v.y);
    }
}

// ---------------- batch-user map ----------------
__global__ void map_build(const int* __restrict__ user, uint32_t* __restrict__ map, int batch) {
    int i = blockIdx.x * blockDim.x + threadIdx.x;
    if (i < batch) atomicMin(&map[user[i]], (uint32_t)i);
}

// ---------------- pass 1: per-(block,bucket) counts, no global atomics ----------------
__global__ __launch_bounds__(TP) void pass1_count(
    const int* __restrict__ ra, int na, const int* __restrict__ ru, int nu,
    const uint32_t* __restrict__ map, int* __restrict__ countsT,
    int nblk, int nbA, int nbTot)
{
    __shared__ int lc[NBMAX];
    const int blk = blockIdx.x;
    for (int i = threadIdx.x; i < nbTot; i += TP) lc[i] = 0;
    __syncthreads();
    const int base = blk * (TP * EP);
    const int n = na + nu;
    for (int i = 0; i < EP; ++i) {
        int e = base + i * TP + threadIdx.x;
        int b = -1;
        if (e < na) {
            b = __builtin_nontemporal_load(ra + e) >> BSHIFT;
        } else if (e < n) {
            int r = __builtin_nontemporal_load(ru + (e - na));
            if (map[r] != 0xFFFFFFFFu) b = nbA + (r >> BSHIFT);
        }
        if (b >= 0) atomicAdd(&lc[b], 1);
    }
    __syncthreads();
    for (int i = threadIdx.x; i < nbTot; i += TP)
        countsT[(size_t)i * nblk + blk] = lc[i];
}

// ---------------- 3-phase exclusive scan over countsT ----------------
#define SCAN_T 256
#define SCAN_E 16

__global__ void scan_blocks(const int* __restrict__ in, int* __restrict__ out,
                            int* __restrict__ sums, int n) {
    __shared__ int smem[SCAN_T];
    const int b = blockIdx.x, tid = threadIdx.x;
    const int base = b * SCAN_T * SCAN_E + tid * SCAN_E;
    int loc[SCAN_E];
    int s = 0;
    for (int i = 0; i < SCAN_E; ++i) {
        int idx = base + i;
        int v = (idx < n) ? in[idx] : 0;
        loc[i] = s; s += v;
    }
    smem[tid] = s; __syncthreads();
    for (int off = 1; off < SCAN_T; off <<= 1) {
        int v = (tid >= off) ? smem[tid - off] : 0;
        __syncthreads();
        smem[tid] += v;
        __syncthreads();
    }
    int pre = (tid == 0) ? 0 : smem[tid - 1];
    if (tid == SCAN_T - 1) sums[b] = smem[tid];
    for (int i = 0; i < SCAN_E; ++i) {
        int idx = base + i;
        if (idx < n) out[idx] = pre + loc[i];
    }
}

__global__ void scan_mid(int* __restrict__ sums, int nb, int* __restrict__ total_out) {
    __shared__ int sh[256];
    const int t = threadIdx.x;
    int v = (t < nb) ? sums[t] : 0;
    sh[t] = v; __syncthreads();
    for (int off = 1; off < 256; off <<= 1) {
        int u = (t >= off) ? sh[t - off] : 0;
        __syncthreads();
        sh[t] += u;
        __syncthreads();
    }
    if (t < nb) sums[t] = sh[t];
    if (t == 255) *total_out = sh[255];
}

__global__ void scan_fixup(int* __restrict__ out, const int* __restrict__ sums, int n) {
    const int b = blockIdx.x;
    if (b == 0) return;
    const int add = sums[b - 1];
    const int base = b * SCAN_T * SCAN_E + threadIdx.x * SCAN_E;
    for (int i = 0; i < SCAN_E; ++i) {
        int idx = base + i;
        if (idx < n) out[idx] += add;
    }
}

__global__ void extract_bases(const int* __restrict__ scanned, int nblk, int nbTot,
                              const int* __restrict__ total, int* __restrict__ bases,
                              int* __restrict__ rpA_end, int nnzA, int* __restrict__ rpU_end) {
    int t = blockIdx.x * blockDim.x + threadIdx.x;
    if (t < nbTot) bases[t] = scanned[(size_t)t * nblk];
    if (t == 0) {
        int tot = *total;
        bases[nbTot] = tot;
        *rpA_end = nnzA;
        *rpU_end = tot - nnzA;
    }
}

// ---------------- pass 2: scatter into bucket-partitioned tmp ----------------
__global__ __launch_bounds__(TP) void pass2_scatter(
    const float* __restrict__ va, const int* __restrict__ ra, const int* __restrict__ ia, int na,
    const float* __restrict__ vu, const int* __restrict__ ru, const int* __restrict__ iu, int nu,
    const uint32_t* __restrict__ map, const int* __restrict__ scanned,
    uint2* __restrict__ tmp, int nblk, int nbA, int nbTot)
{
    __shared__ int cur[NBMAX];
    const int blk = blockIdx.x;
    for (int i = threadIdx.x; i < nbTot; i += TP)
        cur[i] = scanned[(size_t)i * nblk + blk];
    __syncthreads();
    const int base = blk * (TP * EP);
    const int n = na + nu;
    for (int i = 0; i < EP; ++i) {
        int e = base + i * TP + threadIdx.x;
        if (e < na) {
            int r = __builtin_nontemporal_load(ra + e);
            int p = atomicAdd(&cur[r >> BSHIFT], 1);
            uint32_t key = ((uint32_t)(r & 255) << 17) | (uint32_t)__builtin_nontemporal_load(ia + e);
            tmp[p] = make_uint2(key, (uint32_t)__float_as_uint(__builtin_nontemporal_load(va + e)));
        } else if (e < n) {
            int k = e - na;
            int r = __builtin_nontemporal_load(ru + k);
            if (map[r] == 0xFFFFFFFFu) continue;
            int p = atomicAdd(&cur[nbA + (r >> BSHIFT)], 1);
            uint32_t key = ((uint32_t)(r & 255) << 17) | (uint32_t)__builtin_nontemporal_load(iu + k);
            tmp[p] = make_uint2(key, (uint32_t)__float_as_uint(__builtin_nontemporal_load(vu + k)));
        }
    }
}

// ---------------- per-bucket fine sort by (rowlow, col-band) -> packed 4B CSR + rowptr ----------------
__global__ __launch_bounds__(1024) void bucket_sort(const uint2* __restrict__ tmp,
                                                    const int* __restrict__ bases,
                                                    uint32_t* __restrict__ pk,
                                                    int* __restrict__ rpA, int* __restrict__ rpU,
                                                    int nbA, int nnzA, int nItems, int nUsers) {
    __shared__ int h[NBIN];     // histogram -> exclusive offsets -> cursors
    __shared__ int sc[1024];
    const int t = threadIdx.x;
    const int b = blockIdx.x;
    const int lo = bases[b], hi = bases[b + 1];
    const bool isU = (b >= nbA);
    const int rowbase = (isU ? (b - nbA) : b) << BSHIFT;

    for (int i = t; i < NBIN; i += 1024) h[i] = 0;
    __syncthreads();
    for (int i = lo + t; i < hi; i += 1024) {
        uint2 e = tmp[i];
        int key = (int)(((e.x >> 17) << 4) | ((e.x & 0x1FFFFu) >> BANDSH));
        atomicAdd(&h[key], 1);
    }
    __syncthreads();
    // exclusive scan of 4096 bins: 4 bins/thread + block scan of thread sums
    const int b0 = t * 4;
    int s0 = h[b0], s1 = h[b0 + 1], s2 = h[b0 + 2], s3 = h[b0 + 3];
    int tsum = s0 + s1 + s2 + s3;
    sc[t] = tsum; __syncthreads();
    for (int off = 1; off < 1024; off <<= 1) {
        int v = (t >= off) ? sc[t - off] : 0;
        __syncthreads();
        sc[t] += v;
        __syncthreads();
    }
    int excl = sc[t] - tsum;
    h[b0] = excl; h[b0 + 1] = excl + s0; h[b0 + 2] = excl + s0 + s1; h[b0 + 3] = excl + s0 + s1 + s2;
    __syncthreads();
    // rowptr = bucket base + exclusive offset of bin (row, band 0)
    if (t < 256) {
        int row = rowbase + t;
        int gpos = lo + h[t << 4];
        if (isU) { if (row < nUsers) rpU[row] = gpos - nnzA; }
        else     { if (row < nItems) rpA[row] = gpos; }
    }
    __syncthreads();
    // scatter, using h as cursors
    for (int i = lo + t; i < hi; i += 1024) {
        uint2 e = tmp[i];
        uint32_t col = e.x & 0x1FFFFu;
        int key = (int)(((e.x >> 17) << 4) | (col >> BANDSH));
        int p = lo + atomicAdd(&h[key], 1);
        float v = __uint_as_float(e.y);
        uint32_t q = (uint32_t)(v * 32767.0f + 0.5f);
        if (q > 32767u) q = 32767u;
        pk[p] = (col << 15) | q;
    }
}

// ---------------- CSR SpMM, packed 4B elems, bf16 gathers, wave per row, unroll 8 ----------------
#define DECODE(w, v, c) { v = (float)((w) & 0x7FFFu) * (1.0f/32767.0f); c = (int)((w) >> 15); }

#define GATH1(vv, cc) {                                        \
    uint32_t p_ = 0;                                           \
    if (lane < HW) p_ = xbf[(size_t)(cc) * HW + lane];         \
    a0 = fmaf((vv), bflo(p_), a0); a1 = fmaf((vv), bfhi(p_), a1); }

__global__ __launch_bounds__(256) void spmm_pk(
    const uint32_t* __restrict__ pk, const int* __restrict__ rowptr,
    const uint32_t* __restrict__ xbf, uint32_t* __restrict__ outbf,
    const float2* __restrict__ emb2, const uint32_t* __restrict__ x1bf,
    const uint32_t* __restrict__ x2bf, float2* __restrict__ total2,
    uint32_t* __restrict__ totbf, int nrows)
{
    const int wid = (blockIdx.x * blockDim.x + threadIdx.x) >> 6;
    const int lane = threadIdx.x & 63;
    if (wid >= nrows) return;
    const int start = rowptr[wid], end = rowptr[wid + 1];
    float a0 = 0.f, a1 = 0.f;
    for (int base = start; base < end; base += 64) {
        const int nc = min(64, end - base);
        uint32_t w = 0;
        if (lane < nc) w = __builtin_nontemporal_load(pk + base + lane);
        float myv; int myc;
        DECODE(w, myv, myc);
        int t = 0;
        for (; t + 8 <= nc; t += 8) {
            float v0 = __shfl(myv, t),     v1 = __shfl(myv, t + 1);
            float v2 = __shfl(myv, t + 2), v3 = __shfl(myv, t + 3);
            float v4 = __shfl(myv, t + 4), v5 = __shfl(myv, t + 5);
            float v6 = __shfl(myv, t + 6), v7 = __shfl(myv, t + 7);
            int   c0 = __shfl(myc, t),     c1 = __shfl(myc, t + 1);
            int   c2 = __shfl(myc, t + 2), c3 = __shfl(myc, t + 3);
            int   c4 = __shfl(myc, t + 4), c5 = __shfl(myc, t + 5);
            int   c6 = __shfl(myc, t + 6), c7 = __shfl(myc, t + 7);
            uint32_t p0 = 0, p1 = 0, p2 = 0, p3 = 0, p4 = 0, p5 = 0, p6 = 0, p7 = 0;
            if (lane < HW) {
                p0 = xbf[(size_t)c0 * HW + lane];
                p1 = xbf[(size_t)c1 * HW + lane];
                p2 = xbf[(size_t)c2 * HW + lane];
                p3 = xbf[(size_t)c3 * HW + lane];
                p4 = xbf[(size_t)c4 * HW + lane];
                p5 = xbf[(size_t)c5 * HW + lane];
                p6 = xbf[(size_t)c6 * HW + lane];
                p7 = xbf[(size_t)c7 * HW + lane];
            }
            a0 = fmaf(v0, bflo(p0), a0); a1 = fmaf(v0, bfhi(p0), a1);
            a0 = fmaf(v1, bflo(p1), a0); a1 = fmaf(v1, bfhi(p1), a1);
            a0 = fmaf(v2, bflo(p2), a0); a1 = fmaf(v2, bfhi(p2), a1);
            a0 = fmaf(v3, bflo(p3), a0); a1 = fmaf(v3, bfhi(p3), a1);
            a0 = fmaf(v4, bflo(p4), a0); a1 = fmaf(v4, bfhi(p4), a1);
            a0 = fmaf(v5, bflo(p5), a0); a1 = fmaf(v5, bfhi(p5), a1);
            a0 = fmaf(v6, bflo(p6), a0); a1 = fmaf(v6, bfhi(p6), a1);
            a0 = fmaf(v7, bflo(p7), a0); a1 = fmaf(v7, bfhi(p7), a1);
        }
        for (; t + 2 <= nc; t += 2) {
            float v0 = __shfl(myv, t), v1 = __shfl(myv, t + 1);
            int   c0 = __shfl(myc, t), c1 = __shfl(myc, t + 1);
            uint32_t p0 = 0, p1 = 0;
            if (lane < HW) {
                p0 = xbf[(size_t)c0 * HW + lane];
                p1 = xbf[(size_t)c1 * HW + lane];
            }
            a0 = fmaf(v0, bflo(p0), a0); a1 = fmaf(v0, bfhi(p0), a1);
            a0 = fmaf(v1, bflo(p1), a0); a1 = fmaf(v1, bfhi(p1), a1);
        }
        if (t < nc) {
            float v0 = __shfl(myv, t);
            int c0 = __shfl(myc, t);
            GATH1(v0, c0);
        }
    }
    if (lane < HW) {
        const size_t widx = (size_t)wid * HW + lane;
        if (outbf) outbf[widx] = pack_bf16(a0, a1);
        if (total2) {
            float2 e = emb2[widx];
            uint32_t w1 = x1bf[widx], w2 = x2bf[widx];
            float t0 = e.x + bflo(w1) + bflo(w2) + a0;
            float t1 = e.y + bfhi(w1) + bfhi(w2) + a1;
            total2[widx] = make_float2(t0, t1);
            totbf[widx] = pack_bf16(t0, t1);
        }
    }
}

__global__ __launch_bounds__(256) void spmm_batch_pk(
    const uint32_t* __restrict__ pk, const int* __restrict__ rowptr,
    const int* __restrict__ user, const uint32_t* __restrict__ xbf,
    float2* __restrict__ out2, int batch)
{
    const int wid = (blockIdx.x * blockDim.x + threadIdx.x) >> 6;
    const int lane = threadIdx.x & 63;
    if (wid >= batch) return;
    const int row = user[wid];
    const int start = rowptr[row], end = rowptr[row + 1];
    float a0 = 0.f, a1 = 0.f;
    for (int base = start; base < end; base += 64) {
        const int nc = min(64, end - base);
        uint32_t w = 0;
        if (lane < nc) w = __builtin_nontemporal_load(pk + base + lane);
        float myv; int myc;
        DECODE(w, myv, myc);
        int t = 0;
        for (; t + 4 <= nc; t += 4) {
            float v0 = __shfl(myv, t),     v1 = __shfl(myv, t + 1);
            float v2 = __shfl(myv, t + 2), v3 = __shfl(myv, t + 3);
            int   c0 = __shfl(myc, t),     c1 = __shfl(myc, t + 1);
            int   c2 = __shfl(myc, t + 2), c3 = __shfl(myc, t + 3);
            uint32_t p0 = 0, p1 = 0, p2 = 0, p3 = 0;
            if (lane < HW) {
                p0 = xbf[(size_t)c0 * HW + lane];
                p1 = xbf[(size_t)c1 * HW + lane];
                p2 = xbf[(size_t)c2 * HW + lane];
                p3 = xbf[(size_t)c3 * HW + lane];
            }
            a0 = fmaf(v0, bflo(p0), a0); a1 = fmaf(v0, bfhi(p0), a1);
            a0 = fmaf(v1, bflo(p1), a0); a1 = fmaf(v1, bfhi(p1), a1);
            a0 = fmaf(v2, bflo(p2), a0); a1 = fmaf(v2, bfhi(p2), a1);
            a0 = fmaf(v3, bflo(p3), a0); a1 = fmaf(v3, bfhi(p3), a1);
        }
        for (; t < nc; ++t) {
            float v0 = __shfl(myv, t);
            int c0 = __shfl(myc, t);
            GATH1(v0, c0);
        }
    }
    if (lane < HW) out2[(size_t)wid * HW + lane] = make_float2(a0, a1);
}

// ---------------- fallback (round-1) kernels ----------------
__global__ void spmm_scatter(const float* __restrict__ vals, const int* __restrict__ rows,
                             const int* __restrict__ cols, const float* __restrict__ x,
                             float* __restrict__ out, int nnz) {
    long long t = (long long)blockIdx.x * blockDim.x + threadIdx.x;
    int e = (int)(t / V4_PER_ROW);
    int c = (int)(t % V4_PER_ROW);
    if (e >= nnz) return;
    int col = cols[e]; int row = rows[e]; float v = vals[e];
    const float4 g = *(const float4*)(x + (size_t)col * EMB + c * 4);
    float* o = out + (size_t)row * EMB + c * 4;
    atomicAdd(o + 0, v * g.x); atomicAdd(o + 1, v * g.y);
    atomicAdd(o + 2, v * g.z); atomicAdd(o + 3, v * g.w);
}
__global__ void add_inplace(float* __restrict__ acc, const float* __restrict__ x, int n4) {
    int i = blockIdx.x * blockDim.x + threadIdx.x;
    if (i < n4) {
        float4 a = ((const float4*)acc)[i];
        const float4 b = ((const float4*)x)[i];
        a.x += b.x; a.y += b.y; a.z += b.z; a.w += b.w;
        ((float4*)acc)[i] = a;
    }
}
__global__ void gather_rows(const float* __restrict__ src, const int* __restrict__ idx,
                            float* __restrict__ out, int nrows) {
    int t = blockIdx.x * blockDim.x + threadIdx.x;
    int r = t / V4_PER_ROW, c = t % V4_PER_ROW;
    if (r >= nrows) return;
    int s = idx[r];
    *(float4*)(out + (size_t)r * EMB + c * 4) = *(const float4*)(src + (size_t)s * EMB + c * 4);
}

// ---------------- launch ----------------
static inline size_t align256(size_t x) { return (x + 255) & ~(size_t)255; }

extern "C" void kernel_launch(void* const* d_in, const int* in_sizes, int n_in,
                              void* d_out, int out_size, void* d_ws, size_t ws_size,
                              hipStream_t stream) {
    const float* adj_vals  = (const float*)d_in[0];
    const float* u_vals    = (const float*)d_in[1];
    const float* embedding = (const float*)d_in[2];
    const int*   adj_rows  = (const int*)d_in[4];
    const int*   adj_cols  = (const int*)d_in[5];
    const int*   u_rows    = (const int*)d_in[6];
    const int*   u_cols    = (const int*)d_in[7];
    const int*   user      = (const int*)d_in[8];

    const int NNZ_A   = in_sizes[0];
    const int NNZ_U   = in_sizes[1];
    const int N_ITEMS = in_sizes[2] / EMB;
    const int N_USERS = in_sizes[3] / EMB;
    const int BATCH   = in_sizes[8];

    const int NB_A = (N_ITEMS + 255) >> BSHIFT;
    const int NB_U = (N_USERS + 255) >> BSHIFT;
    const int NB_TOT = NB_A + NB_U;

    const int NNZ_T = NNZ_A + NNZ_U;
    const int nblk = (NNZ_T + TP * EP - 1) / (TP * EP);
    const long long nScan = (long long)NB_TOT * nblk;
    const int nsb = (int)((nScan + SCAN_T * SCAN_E - 1) / (SCAN_T * SCAN_E));

    float* total    = (float*)d_out;
    float* out_user = total + (size_t)N_ITEMS * EMB;

    const size_t rowWords = (size_t)N_ITEMS * HW;

    // ---- workspace layout ----
    size_t off = 0;
    char* ws = (char*)d_ws;
    #define WS_ALLOC(name, bytes) char* name = ws + off; off += align256(bytes)
    WS_ALLOC(p_r0,      2 * rowWords * 4);               // x1bf|x2bf, aliased by tmp
    WS_ALLOC(p_ebf,     rowWords * 4);                   // embbf -> totbf
    WS_ALLOC(p_pk,      (size_t)NNZ_T * 4);              // packed CSR (A then U)
    WS_ALLOC(p_rpA,     ((size_t)N_ITEMS + 1) * 4);
    WS_ALLOC(p_rpU,     ((size_t)N_USERS + 1) * 4);
    WS_ALLOC(p_map,     (size_t)N_USERS * 4);
    WS_ALLOC(p_countsT, (size_t)nScan * 4);
    WS_ALLOC(p_sums,    256 * 4);
    WS_ALLOC(p_total,   4);
    WS_ALLOC(p_bases,   ((size_t)NB_TOT + 1) * 4);
    #undef WS_ALLOC
    const size_t tmpBytes = (size_t)NNZ_T * 8;

    if (ws_size >= off && tmpBytes <= 2 * rowWords * 4 && NB_TOT <= NBMAX && nsb <= 256
        && N_ITEMS <= (1 << 17) && N_USERS <= (1 << 17)) {
        uint32_t* x1bf  = (uint32_t*)p_r0;
        uint32_t* x2bf  = (uint32_t*)(p_r0 + rowWords * 4);
        uint2*    tmp   = (uint2*)p_r0;                  // dead before x1bf is written
        uint32_t* embbf = (uint32_t*)p_ebf;
        uint32_t* totbf = (uint32_t*)p_ebf;              // embbf dead after layer 1
        uint32_t* pk    = (uint32_t*)p_pk;
        int* rpA = (int*)p_rpA;
        int* rpU = (int*)p_rpU;
        uint32_t* map = (uint32_t*)p_map;
        int* countsT = (int*)p_countsT;
        int* sums    = (int*)p_sums;
        int* totalN  = (int*)p_total;
        int* bases   = (int*)p_bases;

        hipMemsetAsync(map, 0xFF, (size_t)N_USERS * 4, stream);
        map_build<<<(BATCH + 255) / 256, 256, 0, stream>>>(user, map, BATCH);

        convert_bf16<<<2048, 256, 0, stream>>>((const float2*)embedding, embbf, (int)rowWords);

        pass1_count<<<nblk, TP, 0, stream>>>(adj_rows, NNZ_A, u_rows, NNZ_U, map,
                                             countsT, nblk, NB_A, NB_TOT);
        scan_blocks<<<nsb, SCAN_T, 0, stream>>>(countsT, countsT, sums, (int)nScan);
        scan_mid<<<1, 256, 0, stream>>>(sums, nsb, totalN);
        scan_fixup<<<nsb, SCAN_T, 0, stream>>>(countsT, sums, (int)nScan);
        extract_bases<<<(NB_TOT + 255) / 256, 256, 0, stream>>>(countsT, nblk, NB_TOT, totalN,
                                                                bases, rpA + N_ITEMS, NNZ_A,
                                                                rpU + N_USERS);
        pass2_scatter<<<nblk, TP, 0, stream>>>(adj_vals, adj_rows, adj_cols, NNZ_A,
                                               u_vals, u_rows, u_cols, NNZ_U,
                                               map, countsT, tmp, nblk, NB_A, NB_TOT);
        bucket_sort<<<NB_TOT, 1024, 0, stream>>>(tmp, bases, pk, rpA, rpU,
                                                 NB_A, NNZ_A, N_ITEMS, N_USERS);

        const int gridA = (N_ITEMS + 3) / 4;
        spmm_pk<<<gridA, 256, 0, stream>>>(pk, rpA, embbf, x1bf,
                                           nullptr, nullptr, nullptr, nullptr, nullptr, N_ITEMS);
        spmm_pk<<<gridA, 256, 0, stream>>>(pk, rpA, x1bf, x2bf,
                                           nullptr, nullptr, nullptr, nullptr, nullptr, N_ITEMS);
        spmm_pk<<<gridA, 256, 0, stream>>>(pk, rpA, x2bf, nullptr,
                                           (const float2*)embedding, x1bf, x2bf,
                                           (float2*)total, totbf, N_ITEMS);
        const int gridB = (BATCH + 3) / 4;
        spmm_batch_pk<<<gridB, 256, 0, stream>>>(pk + NNZ_A, rpU, user, totbf,
                                                 (float2*)out_user, BATCH);
    } else {
        // ---- fallback: round-1 atomic path ----
        const size_t itemBytes = (size_t)N_ITEMS * EMB * sizeof(float);
        float* buf0 = (float*)d_ws;
        float* buf1 = buf0 + (size_t)N_ITEMS * EMB;
        float* user_all = buf1;
        const size_t userBytes = (size_t)N_USERS * EMB * sizeof(float);

        hipMemcpyAsync(total, embedding, itemBytes, hipMemcpyDeviceToDevice, stream);
        const int blkA = (NNZ_A * V4_PER_ROW + 255) / 256;
        const int blkU = (NNZ_U * V4_PER_ROW + 255) / 256;
        const int n4 = N_ITEMS * EMB / 4;
        const int blkAdd = (n4 + 255) / 256;

        hipMemsetAsync(buf0, 0, itemBytes, stream);
        spmm_scatter<<<blkA, 256, 0, stream>>>(adj_vals, adj_rows, adj_cols, embedding, buf0, NNZ_A);
        add_inplace<<<blkAdd, 256, 0, stream>>>(total, buf0, n4);
        hipMemsetAsync(buf1, 0, itemBytes, stream);
        spmm_scatter<<<blkA, 256, 0, stream>>>(adj_vals, adj_rows, adj_cols, buf0, buf1, NNZ_A);
        add_inplace<<<blkAdd, 256, 0, stream>>>(total, buf1, n4);
        hipMemsetAsync(buf0, 0, itemBytes, stream);
        spmm_scatter<<<blkA, 256, 0, stream>>>(adj_vals, adj_rows, adj_cols, buf1, buf0, NNZ_A);
        add_inplace<<<blkAdd, 256, 0, stream>>>(total, buf0, n4);
        hipMemsetAsync(user_all, 0, userBytes, stream);
        spmm_scatter<<<blkU, 256, 0, stream>>>(u_vals, u_rows, u_cols, total, user_all, NNZ_U);
        gather_rows<<<(BATCH * V4_PER_ROW + 255) / 256, 256, 0, stream>>>(user_all, user, out_user, BATCH);
    }
}